// Round 4
// baseline (108.676 us; speedup 1.0000x reference)
//
#include <hip/hip_runtime.h>

// Event-to-image: B=16, N=500000 events (t,x,y,p) f32 -> (16,720,1280,3) f32.
// Last-event-wins per pixel: p==1 -> (0,255,255); p==0 -> (255,0,255);
// untouched -> (255,255,510). Order-independent via max over
// key = ((event_idx+1)<<1)|p, packed pk = x<<20 | key (31 bits).
//
// R4: single-pass scatter. R3 read events twice (pass-2 L3 re-read) and spent
// 16 barriers in a Hillis-Steele scan. Now each thread keeps its 32 events in
// registers (pk[32] + y packed in pairs = 48 VGPRs, launch_bounds(256,4) caps
// at 128), shfl-scan (2 barriers), place from registers. Tail events become
// pk=0/y=0 fakes: atomicMax(win, 0) is a no-op, so no guards needed.
// Render uses nontemporal stores for the 177 MB output stream.

#define WIDTH   1280
#define HEIGHT  720
#define BATCH   16
#define NEV     500000
#define THREADS 256
#define EPT     32
#define EVPB    (THREADS * EPT)             // 8192 events per block
#define BPB     ((NEV + EVPB - 1) / EVPB)   // 62 blocks per batch
#define NBLK    (BATCH * BPB)               // 992
#define PH      (HEIGHT + 1)                // 721 prefix entries per block

typedef float f4 __attribute__((ext_vector_type(4)));

// ws layout: [0, NBLK*PH*4)=pref_g (2.86 MB); [0x400000, +NBLK*EVPB*4)=bins (32.5 MB)

__global__ __launch_bounds__(THREADS, 4) void scatter_k(const float4* __restrict__ ev,
                                                        unsigned int* __restrict__ pref_g,
                                                        unsigned int* __restrict__ bins) {
    __shared__ unsigned int hist[HEIGHT];
    __shared__ unsigned int offs[HEIGHT];
    __shared__ unsigned int wtot[4];
    __shared__ unsigned int stage[EVPB];     // 32 KB

    int t = threadIdx.x;
    int batch = blockIdx.x / BPB;
    int blk   = blockIdx.x % BPB;
    int ev0   = blk * EVPB;
    int cnt   = NEV - ev0; if (cnt > EVPB) cnt = EVPB;
    const float4* bev = ev + (size_t)batch * NEV + ev0;

    for (int r = t; r < HEIGHT; r += THREADS) hist[r] = 0u;
    __syncthreads();

    // single pass over global: events -> registers, histogram as we go
    unsigned int pk[EPT];
    unsigned int yp[EPT / 2];
#pragma unroll
    for (int k = 0; k < EPT; ++k) {
        int e = t + k * THREADS;
        unsigned int pkv = 0u, yi = 0u;
        if (e < cnt) {
            float4 v = bev[e];
            yi  = (unsigned int)(int)v.z;
            unsigned int pbit = (v.w == 1.0f) ? 1u : 0u;
            pkv = ((unsigned int)(int)v.y << 20)
                | (((unsigned int)(ev0 + e) + 1u) << 1) | pbit;
        }
        pk[k] = pkv;
        if (k & 1) yp[k >> 1] |= yi << 16; else yp[k >> 1] = yi;
        atomicAdd(&hist[yi], 1u);
    }
    __syncthreads();

    // exclusive prefix over 720 rows: 3 rows/thread, shfl wave scan, 2 barriers
    unsigned int own = 0u;
    int b3 = t * 3;                          // threads 0..239 own rows
    if (t < 240) own = hist[b3] + hist[b3 + 1] + hist[b3 + 2];
    unsigned int incl = own;
    for (int d = 1; d < 64; d <<= 1) {
        unsigned int n = __shfl_up(incl, d);
        if ((t & 63) >= d) incl += n;
    }
    if ((t & 63) == 63) wtot[t >> 6] = incl;
    __syncthreads();
    unsigned int wbase = 0u;
    for (int w = 0; w < (t >> 6); ++w) wbase += wtot[w];
    unsigned int tot4 = wtot[0] + wtot[1] + wtot[2] + wtot[3];   // == EVPB
    if (t < 240) {
        unsigned int run = wbase + incl - own;
        offs[b3] = run;      run += hist[b3];
        offs[b3 + 1] = run;  run += hist[b3 + 1];
        offs[b3 + 2] = run;
    }
    __syncthreads();

    // publish per-block row prefix (coalesced) BEFORE placement mutates offs
    unsigned int* pg = pref_g + (size_t)blockIdx.x * PH;
    for (int r = t; r < PH; r += THREADS)
        pg[r] = (r < HEIGHT) ? offs[r] : tot4;
    __syncthreads();

    // place from registers, sorted by row (fakes land in row 0 with pk=0)
#pragma unroll
    for (int k = 0; k < EPT; ++k) {
        unsigned int yi = (k & 1) ? (yp[k >> 1] >> 16) : (yp[k >> 1] & 0xFFFFu);
        unsigned int slot = atomicAdd(&offs[yi], 1u);
        stage[slot] = pk[k];
    }
    __syncthreads();

    // write the sorted chunk, fully coalesced (keep in L2/L3 for render)
    uint4* dst = (uint4*)(bins + (size_t)blockIdx.x * EVPB);
    const uint4* src = (const uint4*)stage;
    for (int k = t; k < EVPB / 4; k += THREADS)
        dst[k] = src[k];
}

__global__ __launch_bounds__(THREADS) void render_k(const unsigned int* __restrict__ pref_g,
                                                    const unsigned int* __restrict__ bins,
                                                    float4* __restrict__ out) {
    __shared__ unsigned int win[WIDTH];
    __shared__ unsigned int segbase[BPB];
    __shared__ unsigned int segpref[65];

    int t = threadIdx.x;
    int rowid = blockIdx.x;                  // batch*720 + y
    int batch = rowid / HEIGHT;
    int r     = rowid - batch * HEIGHT;

    for (int x = t; x < WIDTH; x += THREADS) win[x] = 0u;

    unsigned int mycnt = 0u;
    if (t < BPB) {
        const unsigned int* pg = pref_g + (size_t)(batch * BPB + t) * PH + r;
        unsigned int p0 = pg[0], p1 = pg[1];
        segbase[t] = (unsigned int)((batch * BPB + t) * EVPB) + p0;
        mycnt = p1 - p0;
    }
    if (t < 64) {                            // wave-0 inclusive scan of 62 counts
        unsigned int v = mycnt;
        for (int d = 1; d < 64; d <<= 1) {
            unsigned int n = __shfl_up(v, d);
            if (t >= d) v += n;
        }
        if (t == 0) segpref[0] = 0u;
        segpref[t + 1] = v;
    }
    __syncthreads();

    unsigned int total = segpref[BPB];       // ~694 (row 0: + fakes, harmless)
    for (unsigned int j = t; j < total; j += THREADS) {
        int lo = 0, hi = BPB - 1;            // largest s with segpref[s] <= j
        while (lo < hi) {
            int mid = (lo + hi + 1) >> 1;
            if (segpref[mid] <= j) lo = mid; else hi = mid - 1;
        }
        unsigned int pk = bins[segbase[lo] + (j - segpref[lo])];
        atomicMax(&win[pk >> 20], pk & 0xFFFFFu);   // LDS atomic; pk==0 no-op
    }
    __syncthreads();

    // write one image row: 1280 px * 3 ch = 960 float4, coalesced, nontemporal
    f4* orow = (f4*)(out + (size_t)rowid * (WIDTH * 3 / 4));
    for (int j = t; j < WIDTH * 3 / 4; j += THREADS) {
        float vals[4];
#pragma unroll
        for (int c = 0; c < 4; ++c) {
            int fi = j * 4 + c;
            int px = fi / 3;
            int ch = fi - px * 3;
            unsigned int k = win[px];
            float val;
            if (k == 0u) val = (ch == 2) ? 510.0f : 255.0f;
            else if (ch == 2) val = 255.0f;
            else if (ch == 0) val = (k & 1u) ? 0.0f : 255.0f;
            else              val = (k & 1u) ? 255.0f : 0.0f;
            vals[c] = val;
        }
        f4 o = { vals[0], vals[1], vals[2], vals[3] };
        __builtin_nontemporal_store(o, orow + j);
    }
}

extern "C" void kernel_launch(void* const* d_in, const int* in_sizes, int n_in,
                              void* d_out, int out_size, void* d_ws, size_t ws_size,
                              hipStream_t stream) {
    const float4* ev = (const float4*)d_in[0];
    unsigned int* pref_g = (unsigned int*)d_ws;
    unsigned int* bins   = (unsigned int*)((char*)d_ws + 0x400000);
    float4* out = (float4*)d_out;

    scatter_k<<<NBLK, THREADS, 0, stream>>>(ev, pref_g, bins);
    render_k<<<BATCH * HEIGHT, THREADS, 0, stream>>>(pref_g, bins, out);
}

// Round 6
// 97.826 us; speedup vs baseline: 1.1109x; 1.1109x over previous
//
#include <hip/hip_runtime.h>

// Event-to-image: B=16, N=500000 events (t,x,y,p) f32 -> (16,720,1280,3) f32.
// Last-event-wins per pixel: p==1 -> (0,255,255); p==0 -> (255,0,255);
// untouched -> (255,255,510). Order-independent via max over
// key = ((event_idx+1)<<1)|p, packed pk = x<<20 | key (31 bits).
//
// R6 = R5 with the compile fix: __builtin_nontemporal_load needs an
// ext_vector_type pointer, not HIP_vector_type (float4). Two-pass scatter
// (proven R3 structure, 101us) + shfl wave-scan (2 barriers) + nontemporal
// render stores + nontemporal pass-2 event re-read.

#define WIDTH   1280
#define HEIGHT  720
#define BATCH   16
#define NEV     500000
#define THREADS 256
#define EPT     32
#define EVPB    (THREADS * EPT)             // 8192 events per block
#define BPB     ((NEV + EVPB - 1) / EVPB)   // 62 blocks per batch
#define NBLK    (BATCH * BPB)               // 992
#define PH      (HEIGHT + 1)                // 721 prefix entries per block

typedef float f4 __attribute__((ext_vector_type(4)));

// ws layout: [0, NBLK*PH*4)=pref_g (2.86 MB); [0x400000, +NBLK*EVPB*4)=bins (32.5 MB)

__global__ __launch_bounds__(THREADS) void scatter_k(const float4* __restrict__ ev,
                                                     unsigned int* __restrict__ pref_g,
                                                     unsigned int* __restrict__ bins) {
    __shared__ unsigned int hist[HEIGHT];
    __shared__ unsigned int offs[HEIGHT];
    __shared__ unsigned int wtot[4];
    __shared__ unsigned int stage[EVPB];     // 32 KB

    int t = threadIdx.x;
    int batch = blockIdx.x / BPB;
    int blk   = blockIdx.x % BPB;
    int ev0   = blk * EVPB;
    int cnt   = NEV - ev0; if (cnt > EVPB) cnt = EVPB;
    const float4* bev = ev + (size_t)batch * NEV + ev0;
    const f4* bevv = (const f4*)bev;

    for (int r = t; r < HEIGHT; r += THREADS) hist[r] = 0u;
    __syncthreads();

    // pass 1: row histogram (streams events through L2; pass 2 re-hits)
    for (int k = 0; k < EPT; ++k) {
        int e = t + k * THREADS;
        if (e < cnt) {
            float4 v = bev[e];
            atomicAdd(&hist[(int)v.z], 1u);
        }
    }
    __syncthreads();

    // exclusive prefix over 720 rows: 3 rows/thread, shfl wave scan, 2 barriers
    unsigned int own = 0u;
    int b3 = t * 3;                          // threads 0..239 own rows
    if (t < 240) own = hist[b3] + hist[b3 + 1] + hist[b3 + 2];
    unsigned int incl = own;
    for (int d = 1; d < 64; d <<= 1) {
        unsigned int n = __shfl_up(incl, d);
        if ((t & 63) >= d) incl += n;
    }
    if ((t & 63) == 63) wtot[t >> 6] = incl;
    __syncthreads();
    unsigned int wbase = 0u;
    for (int w = 0; w < (t >> 6); ++w) wbase += wtot[w];
    unsigned int total = wtot[0] + wtot[1] + wtot[2] + wtot[3];   // == cnt
    if (t < 240) {
        unsigned int run = wbase + incl - own;
        offs[b3] = run;      run += hist[b3];
        offs[b3 + 1] = run;  run += hist[b3 + 1];
        offs[b3 + 2] = run;
    }
    __syncthreads();

    // publish per-block row prefix (coalesced) BEFORE pass 2 mutates offs
    unsigned int* pg = pref_g + (size_t)blockIdx.x * PH;
    for (int r = t; r < PH; r += THREADS)
        pg[r] = (r < HEIGHT) ? offs[r] : total;
    __syncthreads();

    // pass 2: re-read (L2 hit; nt = last use, keep L2 for bins) and place sorted
    for (int k = 0; k < EPT; ++k) {
        int e = t + k * THREADS;
        if (e < cnt) {
            f4 v = __builtin_nontemporal_load(&bevv[e]);
            int xi = (int)v.y;
            int yi = (int)v.z;
            unsigned int pbit = (v.w == 1.0f) ? 1u : 0u;
            unsigned int key  = (((unsigned int)(ev0 + e) + 1u) << 1) | pbit;  // 20 bits
            unsigned int pk   = ((unsigned int)xi << 20) | key;
            unsigned int slot = atomicAdd(&offs[yi], 1u);                      // < cnt
            stage[slot] = pk;
        }
    }
    __syncthreads();

    // write the sorted chunk, fully coalesced (keep in L2/L3 for render)
    uint4* dst = (uint4*)(bins + (size_t)blockIdx.x * EVPB);
    const uint4* src = (const uint4*)stage;
    for (int k = t; k < EVPB / 4; k += THREADS)
        dst[k] = src[k];
}

__global__ __launch_bounds__(THREADS) void render_k(const unsigned int* __restrict__ pref_g,
                                                    const unsigned int* __restrict__ bins,
                                                    float4* __restrict__ out) {
    __shared__ unsigned int win[WIDTH];
    __shared__ unsigned int segbase[BPB];
    __shared__ unsigned int segpref[65];

    int t = threadIdx.x;
    int rowid = blockIdx.x;                  // batch*720 + y
    int batch = rowid / HEIGHT;
    int r     = rowid - batch * HEIGHT;

    for (int x = t; x < WIDTH; x += THREADS) win[x] = 0u;

    unsigned int mycnt = 0u;
    if (t < BPB) {
        const unsigned int* pg = pref_g + (size_t)(batch * BPB + t) * PH + r;
        unsigned int p0 = pg[0], p1 = pg[1];
        segbase[t] = (unsigned int)((batch * BPB + t) * EVPB) + p0;
        mycnt = p1 - p0;
    }
    if (t < 64) {                            // wave-0 inclusive scan of 62 counts
        unsigned int v = mycnt;
        for (int d = 1; d < 64; d <<= 1) {
            unsigned int n = __shfl_up(v, d);
            if (t >= d) v += n;
        }
        if (t == 0) segpref[0] = 0u;
        segpref[t + 1] = v;
    }
    __syncthreads();

    unsigned int total = segpref[BPB];       // ~694
    for (unsigned int j = t; j < total; j += THREADS) {
        int lo = 0, hi = BPB - 1;            // largest s with segpref[s] <= j
        while (lo < hi) {
            int mid = (lo + hi + 1) >> 1;
            if (segpref[mid] <= j) lo = mid; else hi = mid - 1;
        }
        unsigned int pk = bins[segbase[lo] + (j - segpref[lo])];
        atomicMax(&win[pk >> 20], pk & 0xFFFFFu);   // LDS atomic
    }
    __syncthreads();

    // write one image row: 1280 px * 3 ch = 960 float4, coalesced, nontemporal
    f4* orow = (f4*)(out + (size_t)rowid * (WIDTH * 3 / 4));
    for (int j = t; j < WIDTH * 3 / 4; j += THREADS) {
        float vals[4];
#pragma unroll
        for (int c = 0; c < 4; ++c) {
            int fi = j * 4 + c;
            int px = fi / 3;
            int ch = fi - px * 3;
            unsigned int k = win[px];
            float val;
            if (k == 0u) val = (ch == 2) ? 510.0f : 255.0f;
            else if (ch == 2) val = 255.0f;
            else if (ch == 0) val = (k & 1u) ? 0.0f : 255.0f;
            else              val = (k & 1u) ? 255.0f : 0.0f;
            vals[c] = val;
        }
        f4 o = { vals[0], vals[1], vals[2], vals[3] };
        __builtin_nontemporal_store(o, orow + j);
    }
}

extern "C" void kernel_launch(void* const* d_in, const int* in_sizes, int n_in,
                              void* d_out, int out_size, void* d_ws, size_t ws_size,
                              hipStream_t stream) {
    const float4* ev = (const float4*)d_in[0];
    unsigned int* pref_g = (unsigned int*)d_ws;
    unsigned int* bins   = (unsigned int*)((char*)d_ws + 0x400000);
    float4* out = (float4*)d_out;

    scatter_k<<<NBLK, THREADS, 0, stream>>>(ev, pref_g, bins);
    render_k<<<BATCH * HEIGHT, THREADS, 0, stream>>>(pref_g, bins, out);
}